// Round 1
// baseline (411.454 us; speedup 1.0000x reference)
//
#include <hip/hip_runtime.h>

#define Hh 128
#define Ww 160
#define Cc 1024
#define HWp (Hh*Ww)

// ---------------------------------------------------------------------------
// Wave-wide max reduction (wave64). All lanes return the max.
__device__ __forceinline__ float waveMax(float v) {
    #pragma unroll
    for (int off = 1; off < 64; off <<= 1)
        v = fmaxf(v, __shfl_xor(v, off, 64));
    return v;
}

// ---------------------------------------------------------------------------
// Normalize guidance: g (20, H, W) -> kn tables.
// dir 0,1 (H-scans): kn[d*HW*5 + (t*H + s)*5 + j]   (per-column contiguous)
// dir 2,3 (W-scans): kn[d*HW*5 + (s*W + t)*5 + j]   (per-row contiguous)
__global__ __launch_bounds__(256) void norm_g(const float* __restrict__ g,
                                              float* __restrict__ kn)
{
    int p = blockIdx.x * blockDim.x + threadIdx.x;
    if (p >= HWp) return;
    int s = p / Ww, t = p - s * Ww;
    #pragma unroll
    for (int d = 0; d < 4; ++d) {
        float v[5]; float sum = 0.f;
        #pragma unroll
        for (int j = 0; j < 5; ++j) {
            v[j] = g[(size_t)(5 * d + j) * HWp + p];
            sum += fabsf(v[j]);
        }
        float inv = 1.f / fmaxf(sum, 1e-12f);
        size_t off = (d < 2) ? ((size_t)d * HWp * 5 + ((size_t)t * Hh + s) * 5)
                             : ((size_t)d * HWp * 5 + (size_t)p * 5);
        #pragma unroll
        for (int j = 0; j < 5; ++j) kn[off + j] = v[j] * inv;
    }
}

// ---------------------------------------------------------------------------
// Tiled transposes between (C, HW) and (HW, C).
__global__ __launch_bounds__(256) void transpose_in(const float* __restrict__ in,
                                                    float* __restrict__ out)
{
    __shared__ float tile[32][33];
    int p0 = blockIdx.x * 32, c0 = blockIdx.y * 32;
    int tx = threadIdx.x, ty = threadIdx.y;          // (32, 8)
    #pragma unroll
    for (int i = 0; i < 4; ++i)
        tile[ty + 8 * i][tx] = in[(size_t)(c0 + ty + 8 * i) * HWp + p0 + tx];
    __syncthreads();
    #pragma unroll
    for (int i = 0; i < 4; ++i)
        out[(size_t)(p0 + ty + 8 * i) * Cc + c0 + tx] = tile[tx][ty + 8 * i];
}

__global__ __launch_bounds__(256) void transpose_out(const float* __restrict__ Y,
                                                     float* __restrict__ out)
{
    __shared__ float tile[32][33];
    int c0 = blockIdx.x * 32, p0 = blockIdx.y * 32;
    int tx = threadIdx.x, ty = threadIdx.y;          // (32, 8)
    #pragma unroll
    for (int i = 0; i < 4; ++i)
        tile[ty + 8 * i][tx] = Y[(size_t)(p0 + ty + 8 * i) * Cc + c0 + tx];
    __syncthreads();
    #pragma unroll
    for (int i = 0; i < 4; ++i)
        out[(size_t)(c0 + ty + 8 * i) * HWp + p0 + tx] = tile[tx][ty + 8 * i];
}

// ---------------------------------------------------------------------------
// One directional scan pass, in-place on Y laid out (H, W, C).
// One wave (64 lanes) per scan chain. Lane l owns channels 256q + 4l + e,
// q=0..3, e=0..3 (4 float4 chunks) -> perfectly coalesced float4 access.
// Recurrence: out = k0*x + k1*prev + k2*prev[c-1] + k3*prev[c+1] + k4*max_c(prev)
// Boundary slice: out = x (no work; in-place means nothing to store).
__global__ __launch_bounds__(64) void scan_pass(
    float* __restrict__ Y, const float* __restrict__ ktab,
    int nsteps, long stride, long colstride, int fwd)
{
    __shared__ float ks[Ww * 5];                     // up to 800 floats
    const int l = threadIdx.x;

    // Preload this chain's k-tuples (contiguous by construction).
    const float* kt = ktab + (size_t)blockIdx.x * (size_t)nsteps * 5u;
    for (int i = l; i < nsteps * 5; i += 64) ks[i] = kt[i];
    __syncthreads();

    long base = (long)blockIdx.x * colstride;
    long sstep = stride;
    int kidx = 0, kstep = 1;
    if (!fwd) {
        base += (long)(nsteps - 1) * stride;
        sstep = -stride; kidx = nsteps - 1; kstep = -1;
    }

    float4 prev[4], xq[4];
    #pragma unroll
    for (int q = 0; q < 4; ++q)
        prev[q] = *reinterpret_cast<const float4*>(&Y[base + q * 256 + 4 * l]);

    float mx = -3.4e38f;
    #pragma unroll
    for (int q = 0; q < 4; ++q)
        mx = fmaxf(mx, fmaxf(fmaxf(prev[q].x, prev[q].y),
                             fmaxf(prev[q].z, prev[q].w)));
    float pmax = waveMax(mx);

    // prefetch step 1
    long nbase = base + sstep;
    #pragma unroll
    for (int q = 0; q < 4; ++q)
        xq[q] = *reinterpret_cast<const float4*>(&Y[nbase + q * 256 + 4 * l]);

    for (int i = 1; i < nsteps; ++i) {
        base = nbase;
        kidx += kstep;
        float k0 = ks[kidx * 5 + 0], k1 = ks[kidx * 5 + 1], k2 = ks[kidx * 5 + 2],
              k3 = ks[kidx * 5 + 3], k4 = ks[kidx * 5 + 4];

        float4 xc[4];
        #pragma unroll
        for (int q = 0; q < 4; ++q) xc[q] = xq[q];

        // prefetch next step's x while we compute
        if (i + 1 < nsteps) {
            nbase = base + sstep;
            #pragma unroll
            for (int q = 0; q < 4; ++q)
                xq[q] = *reinterpret_cast<const float4*>(&Y[nbase + q * 256 + 4 * l]);
        }

        // cross-lane neighbor values from prev
        float up[4], dn[4], bup[4], bdn[4];
        #pragma unroll
        for (int q = 0; q < 4; ++q) {
            up[q]  = __shfl_up(prev[q].w, 1, 64);     // lane l-1's last elem
            dn[q]  = __shfl_down(prev[q].x, 1, 64);   // lane l+1's first elem
            bup[q] = __shfl(prev[q].w, 63, 64);       // chunk q's global last
            bdn[q] = __shfl(prev[q].x, 0, 64);        // chunk q's global first
        }

        float4 out[4]; float m = -3.4e38f;
        #pragma unroll
        for (int q = 0; q < 4; ++q) {
            float pm0 = (l > 0)  ? up[q] : (q > 0 ? bup[q - 1] : 0.f);
            float pp3 = (l < 63) ? dn[q] : (q < 3 ? bdn[q + 1] : 0.f);
            float4 p = prev[q], x = xc[q];
            float o0 = k0 * x.x + k1 * p.x + k2 * pm0 + k3 * p.y + k4 * pmax;
            float o1 = k0 * x.y + k1 * p.y + k2 * p.x + k3 * p.z + k4 * pmax;
            float o2 = k0 * x.z + k1 * p.z + k2 * p.y + k3 * p.w + k4 * pmax;
            float o3 = k0 * x.w + k1 * p.w + k2 * p.z + k3 * pp3 + k4 * pmax;
            out[q] = make_float4(o0, o1, o2, o3);
            m = fmaxf(m, fmaxf(fmaxf(o0, o1), fmaxf(o2, o3)));
        }

        #pragma unroll
        for (int q = 0; q < 4; ++q)
            *reinterpret_cast<float4*>(&Y[base + q * 256 + 4 * l]) = out[q];

        pmax = waveMax(m);
        #pragma unroll
        for (int q = 0; q < 4; ++q) prev[q] = out[q];
    }
}

// ---------------------------------------------------------------------------
extern "C" void kernel_launch(void* const* d_in, const int* in_sizes, int n_in,
                              void* d_out, int out_size, void* d_ws, size_t ws_size,
                              hipStream_t stream)
{
    const float* x = (const float*)d_in[0];   // (1, 32, 32, 128, 160) = (C,H,W)
    const float* g = (const float*)d_in[1];   // (1, 20, 128, 160)
    float* out = (float*)d_out;

    const size_t kn_bytes = (size_t)4 * HWp * 5 * sizeof(float);   // 1.64 MB
    const size_t y_bytes  = (size_t)Cc * HWp * sizeof(float);      // 84 MB
    if (ws_size < kn_bytes + y_bytes) return;   // workspace too small: bail cleanly

    float* kn = (float*)d_ws;
    float* Y  = (float*)((char*)d_ws + kn_bytes);   // kn_bytes is 256B-aligned

    // 1) normalize guidance into per-chain-contiguous tables
    norm_g<<<(HWp + 255) / 256, 256, 0, stream>>>(g, kn);

    // 2) transpose x (C,HW) -> Y (HW,C)
    transpose_in<<<dim3(HWp / 32, Cc / 32), dim3(32, 8), 0, stream>>>(x, Y);

    // 3) four in-place directional scans on Y
    // down:  scan s forward, one block per column t
    scan_pass<<<Ww, 64, 0, stream>>>(Y, kn + (size_t)0 * HWp * 5,
                                     Hh, (long)Ww * Cc, (long)Cc, 1);
    // up:    scan s backward
    scan_pass<<<Ww, 64, 0, stream>>>(Y, kn + (size_t)1 * HWp * 5,
                                     Hh, (long)Ww * Cc, (long)Cc, 0);
    // right: scan t forward, one block per row s
    scan_pass<<<Hh, 64, 0, stream>>>(Y, kn + (size_t)2 * HWp * 5,
                                     Ww, (long)Cc, (long)Ww * Cc, 1);
    // left:  scan t backward
    scan_pass<<<Hh, 64, 0, stream>>>(Y, kn + (size_t)3 * HWp * 5,
                                     Ww, (long)Cc, (long)Ww * Cc, 0);

    // 4) transpose Y (HW,C) -> out (C,HW)
    transpose_out<<<dim3(Cc / 32, HWp / 32), dim3(32, 8), 0, stream>>>(Y, out);
}

// Round 2
// 396.336 us; speedup vs baseline: 1.0381x; 1.0381x over previous
//
#include <hip/hip_runtime.h>

#define Hh 128
#define Ww 160
#define Cc 1024
#define HWp (Hh*Ww)

// ---------------------------------------------------------------------------
// Wave-wide max reduction (wave64). All lanes return the max.
__device__ __forceinline__ float waveMax(float v) {
    #pragma unroll
    for (int off = 1; off < 64; off <<= 1)
        v = fmaxf(v, __shfl_xor(v, off, 64));
    return v;
}

// ---------------------------------------------------------------------------
// Normalize guidance: g (20, H, W) -> kn tables.
// dir 0,1 (H-scans): kn[d*HW*5 + (t*H + s)*5 + j]   (per-column contiguous)
// dir 2,3 (W-scans): kn[d*HW*5 + (s*W + t)*5 + j]   (per-row contiguous)
__global__ __launch_bounds__(256) void norm_g(const float* __restrict__ g,
                                              float* __restrict__ kn)
{
    int p = blockIdx.x * blockDim.x + threadIdx.x;
    if (p >= HWp) return;
    int s = p / Ww, t = p - s * Ww;
    #pragma unroll
    for (int d = 0; d < 4; ++d) {
        float v[5]; float sum = 0.f;
        #pragma unroll
        for (int j = 0; j < 5; ++j) {
            v[j] = g[(size_t)(5 * d + j) * HWp + p];
            sum += fabsf(v[j]);
        }
        float inv = 1.f / fmaxf(sum, 1e-12f);
        size_t off = (d < 2) ? ((size_t)d * HWp * 5 + ((size_t)t * Hh + s) * 5)
                             : ((size_t)d * HWp * 5 + (size_t)p * 5);
        #pragma unroll
        for (int j = 0; j < 5; ++j) kn[off + j] = v[j] * inv;
    }
}

// ---------------------------------------------------------------------------
// Tiled transposes between (C, HW) and (HW, C).
__global__ __launch_bounds__(256) void transpose_in(const float* __restrict__ in,
                                                    float* __restrict__ out)
{
    __shared__ float tile[32][33];
    int p0 = blockIdx.x * 32, c0 = blockIdx.y * 32;
    int tx = threadIdx.x, ty = threadIdx.y;          // (32, 8)
    #pragma unroll
    for (int i = 0; i < 4; ++i)
        tile[ty + 8 * i][tx] = in[(size_t)(c0 + ty + 8 * i) * HWp + p0 + tx];
    __syncthreads();
    #pragma unroll
    for (int i = 0; i < 4; ++i)
        out[(size_t)(p0 + ty + 8 * i) * Cc + c0 + tx] = tile[tx][ty + 8 * i];
}

__global__ __launch_bounds__(256) void transpose_out(const float* __restrict__ Y,
                                                     float* __restrict__ out)
{
    __shared__ float tile[32][33];
    int c0 = blockIdx.x * 32, p0 = blockIdx.y * 32;
    int tx = threadIdx.x, ty = threadIdx.y;          // (32, 8)
    #pragma unroll
    for (int i = 0; i < 4; ++i)
        tile[ty + 8 * i][tx] = Y[(size_t)(p0 + ty + 8 * i) * Cc + c0 + tx];
    __syncthreads();
    #pragma unroll
    for (int i = 0; i < 4; ++i)
        out[(size_t)(c0 + ty + 8 * i) * HWp + p0 + tx] = tile[tx][ty + 8 * i];
}

// ---------------------------------------------------------------------------
// One directional scan pass, in-place on Y laid out (H, W, C).
// One wave per chain; lane l owns channels 256q+4l+e (4 coalesced float4s).
// Depth-3 x-prefetch (xb0/xb1/xb2, statically indexed via 3x-unrolled loop).
// Max de-chained: out = partial + k4*pmax adds the same constant to all
// channels, so max(out) = waveMax(partial) + k4*pmax -> the wave reduce runs
// off the recurrence critical path; pmax chain is 1 FMA/step.
__global__ __launch_bounds__(64) void scan_pass(
    float* __restrict__ Y, const float* __restrict__ ktab,
    int nsteps, long stride, long colstride, int fwd)
{
    __shared__ float ks[Ww * 5];                     // up to 800 floats
    const int l = threadIdx.x;

    const float* kt = ktab + (size_t)blockIdx.x * (size_t)nsteps * 5u;
    for (int i = l; i < nsteps * 5; i += 64) ks[i] = kt[i];
    __syncthreads();

    long cur = (long)blockIdx.x * colstride;
    long sstep = stride;
    int kidx = 0, kstep = 1;
    if (!fwd) {
        cur += (long)(nsteps - 1) * stride;
        sstep = -stride; kidx = nsteps - 1; kstep = -1;
    }
    const int loff = 4 * l;
    const long p3 = 3 * sstep;

    // step 0: out = x (in-place: nothing to store)
    float4 prev[4];
    #pragma unroll
    for (int q = 0; q < 4; ++q)
        prev[q] = *reinterpret_cast<const float4*>(&Y[cur + q * 256 + loff]);
    float mx = -3.4e38f;
    #pragma unroll
    for (int q = 0; q < 4; ++q)
        mx = fmaxf(mx, fmaxf(fmaxf(prev[q].x, prev[q].y),
                             fmaxf(prev[q].z, prev[q].w)));
    float pmax = waveMax(mx);

    // prefetch x for steps 1,2,3 (nsteps >= 128 always)
    float4 xb0[4], xb1[4], xb2[4];
    #pragma unroll
    for (int q = 0; q < 4; ++q)
        xb0[q] = *reinterpret_cast<const float4*>(&Y[cur + sstep + q * 256 + loff]);
    #pragma unroll
    for (int q = 0; q < 4; ++q)
        xb1[q] = *reinterpret_cast<const float4*>(&Y[cur + 2 * sstep + q * 256 + loff]);
    #pragma unroll
    for (int q = 0; q < 4; ++q)
        xb2[q] = *reinterpret_cast<const float4*>(&Y[cur + 3 * sstep + q * 256 + loff]);

    cur += sstep;   // now at step 1
    int i = 1;

#define STEP(XB)                                                              \
  {                                                                           \
    kidx += kstep;                                                            \
    const float k0 = ks[kidx * 5 + 0], k1 = ks[kidx * 5 + 1],                 \
                k2 = ks[kidx * 5 + 2], k3 = ks[kidx * 5 + 3],                 \
                k4 = ks[kidx * 5 + 4];                                        \
    float up[4], dn[4], bup[4], bdn[4];                                       \
    _Pragma("unroll") for (int q = 0; q < 4; ++q) {                           \
      up[q]  = __shfl_up(prev[q].w, 1, 64);                                   \
      dn[q]  = __shfl_down(prev[q].x, 1, 64);                                 \
      bup[q] = __shfl(prev[q].w, 63, 64);                                     \
      bdn[q] = __shfl(prev[q].x, 0, 64);                                      \
    }                                                                         \
    float4 pt[4]; float m = -3.4e38f;                                         \
    _Pragma("unroll") for (int q = 0; q < 4; ++q) {                           \
      float pm0 = (l > 0)  ? up[q] : (q > 0 ? bup[q - 1] : 0.f);              \
      float pp3 = (l < 63) ? dn[q] : (q < 3 ? bdn[q + 1] : 0.f);              \
      float4 p = prev[q], x = XB[q];                                          \
      pt[q].x = k0 * x.x + k1 * p.x + k2 * pm0 + k3 * p.y;                    \
      pt[q].y = k0 * x.y + k1 * p.y + k2 * p.x + k3 * p.z;                    \
      pt[q].z = k0 * x.z + k1 * p.z + k2 * p.y + k3 * p.w;                    \
      pt[q].w = k0 * x.w + k1 * p.w + k2 * p.z + k3 * pp3;                    \
      m = fmaxf(m, fmaxf(fmaxf(pt[q].x, pt[q].y), fmaxf(pt[q].z, pt[q].w))); \
    }                                                                         \
    if (i + 3 < nsteps) {                                                     \
      _Pragma("unroll") for (int q = 0; q < 4; ++q)                           \
        XB[q] = *reinterpret_cast<const float4*>(&Y[cur + p3 + q * 256 + loff]); \
    }                                                                         \
    float R = waveMax(m);                                                     \
    _Pragma("unroll") for (int q = 0; q < 4; ++q) {                           \
      prev[q].x = fmaf(k4, pmax, pt[q].x);                                    \
      prev[q].y = fmaf(k4, pmax, pt[q].y);                                    \
      prev[q].z = fmaf(k4, pmax, pt[q].z);                                    \
      prev[q].w = fmaf(k4, pmax, pt[q].w);                                    \
      *reinterpret_cast<float4*>(&Y[cur + q * 256 + loff]) = prev[q];         \
    }                                                                         \
    pmax = fmaf(k4, pmax, R);                                                 \
    cur += sstep; ++i;                                                        \
  }

    // 3x-unrolled main loop: slots cycle xb0,xb1,xb2 starting at step 1.
    while (i + 2 < nsteps) { STEP(xb0) STEP(xb1) STEP(xb2) }
    if (i < nsteps) STEP(xb0)
    if (i < nsteps) STEP(xb1)
#undef STEP
}

// ---------------------------------------------------------------------------
extern "C" void kernel_launch(void* const* d_in, const int* in_sizes, int n_in,
                              void* d_out, int out_size, void* d_ws, size_t ws_size,
                              hipStream_t stream)
{
    const float* x = (const float*)d_in[0];   // (1, 32, 32, 128, 160) = (C,H,W)
    const float* g = (const float*)d_in[1];   // (1, 20, 128, 160)
    float* out = (float*)d_out;

    const size_t kn_bytes = (size_t)4 * HWp * 5 * sizeof(float);   // 1.64 MB
    const size_t y_bytes  = (size_t)Cc * HWp * sizeof(float);      // 84 MB
    if (ws_size < kn_bytes + y_bytes) return;

    float* kn = (float*)d_ws;
    float* Y  = (float*)((char*)d_ws + kn_bytes);

    // 1) normalize guidance into per-chain-contiguous tables
    norm_g<<<(HWp + 255) / 256, 256, 0, stream>>>(g, kn);

    // 2) transpose x (C,HW) -> Y (HW,C)
    transpose_in<<<dim3(HWp / 32, Cc / 32), dim3(32, 8), 0, stream>>>(x, Y);

    // 3) four in-place directional scans on Y
    scan_pass<<<Ww, 64, 0, stream>>>(Y, kn + (size_t)0 * HWp * 5,
                                     Hh, (long)Ww * Cc, (long)Cc, 1);
    scan_pass<<<Ww, 64, 0, stream>>>(Y, kn + (size_t)1 * HWp * 5,
                                     Hh, (long)Ww * Cc, (long)Cc, 0);
    scan_pass<<<Hh, 64, 0, stream>>>(Y, kn + (size_t)2 * HWp * 5,
                                     Ww, (long)Cc, (long)Ww * Cc, 1);
    scan_pass<<<Hh, 64, 0, stream>>>(Y, kn + (size_t)3 * HWp * 5,
                                     Ww, (long)Cc, (long)Ww * Cc, 0);

    // 4) transpose Y (HW,C) -> out (C,HW)
    transpose_out<<<dim3(Cc / 32, HWp / 32), dim3(32, 8), 0, stream>>>(Y, out);
}

// Round 3
// 288.450 us; speedup vs baseline: 1.4264x; 1.3740x over previous
//
#include <hip/hip_runtime.h>

#define Hh 128
#define Ww 160
#define Cc 1024
#define HWp (Hh*Ww)

// ---------------------------------------------------------------------------
// DPP cross-lane helpers (VALU latency, no LDS/ds_bpermute).
template<int CTRL>
__device__ __forceinline__ float dppMaxStage(float v) {
    // invalid lanes receive old = -inf (identity for max)
    int t = __builtin_amdgcn_update_dpp((int)0xFF800000, __float_as_int(v),
                                        CTRL, 0xF, 0xF, false);
    return fmaxf(v, __int_as_float(t));
}
// Wave64 max; result returned as a wave-uniform (SGPR) value.
__device__ __forceinline__ float waveMaxDpp(float v) {
    v = dppMaxStage<0x111>(v);   // row_shr:1
    v = dppMaxStage<0x112>(v);   // row_shr:2
    v = dppMaxStage<0x114>(v);   // row_shr:4
    v = dppMaxStage<0x118>(v);   // row_shr:8
    v = dppMaxStage<0x142>(v);   // row_bcast:15
    v = dppMaxStage<0x143>(v);   // row_bcast:31  -> lane63 = wave max
    return __int_as_float(__builtin_amdgcn_readlane(__float_as_int(v), 63));
}
__device__ __forceinline__ float dppRor1(float v) {  // lane l <- lane (l-1)&63
    return __int_as_float(__builtin_amdgcn_update_dpp(0, __float_as_int(v),
                                                      0x13C, 0xF, 0xF, false));
}
__device__ __forceinline__ float dppRol1(float v) {  // lane l <- lane (l+1)&63
    return __int_as_float(__builtin_amdgcn_update_dpp(0, __float_as_int(v),
                                                      0x134, 0xF, 0xF, false));
}

// ---------------------------------------------------------------------------
// Normalize guidance: g (20, H, W) -> kn tables.
// dir 0,1 (H-scans): kn[d*HW*5 + (t*H + s)*5 + j]   (per-column contiguous)
// dir 2,3 (W-scans): kn[d*HW*5 + (s*W + t)*5 + j]   (per-row contiguous)
__global__ __launch_bounds__(256) void norm_g(const float* __restrict__ g,
                                              float* __restrict__ kn)
{
    int p = blockIdx.x * blockDim.x + threadIdx.x;
    if (p >= HWp) return;
    int s = p / Ww, t = p - s * Ww;
    #pragma unroll
    for (int d = 0; d < 4; ++d) {
        float v[5]; float sum = 0.f;
        #pragma unroll
        for (int j = 0; j < 5; ++j) {
            v[j] = g[(size_t)(5 * d + j) * HWp + p];
            sum += fabsf(v[j]);
        }
        float inv = 1.f / fmaxf(sum, 1e-12f);
        size_t off = (d < 2) ? ((size_t)d * HWp * 5 + ((size_t)t * Hh + s) * 5)
                             : ((size_t)d * HWp * 5 + (size_t)p * 5);
        #pragma unroll
        for (int j = 0; j < 5; ++j) kn[off + j] = v[j] * inv;
    }
}

// ---------------------------------------------------------------------------
// Tiled transposes between (C, HW) and (HW, C).
__global__ __launch_bounds__(256) void transpose_in(const float* __restrict__ in,
                                                    float* __restrict__ out)
{
    __shared__ float tile[32][33];
    int p0 = blockIdx.x * 32, c0 = blockIdx.y * 32;
    int tx = threadIdx.x, ty = threadIdx.y;          // (32, 8)
    #pragma unroll
    for (int i = 0; i < 4; ++i)
        tile[ty + 8 * i][tx] = in[(size_t)(c0 + ty + 8 * i) * HWp + p0 + tx];
    __syncthreads();
    #pragma unroll
    for (int i = 0; i < 4; ++i)
        out[(size_t)(p0 + ty + 8 * i) * Cc + c0 + tx] = tile[tx][ty + 8 * i];
}

__global__ __launch_bounds__(256) void transpose_out(const float* __restrict__ Y,
                                                     float* __restrict__ out)
{
    __shared__ float tile[32][33];
    int c0 = blockIdx.x * 32, p0 = blockIdx.y * 32;
    int tx = threadIdx.x, ty = threadIdx.y;          // (32, 8)
    #pragma unroll
    for (int i = 0; i < 4; ++i)
        tile[ty + 8 * i][tx] = Y[(size_t)(p0 + ty + 8 * i) * Cc + c0 + tx];
    __syncthreads();
    #pragma unroll
    for (int i = 0; i < 4; ++i)
        out[(size_t)(c0 + ty + 8 * i) * HWp + p0 + tx] = tile[tx][ty + 8 * i];
}

// ---------------------------------------------------------------------------
// One directional scan pass, in-place on Y laid out (H, W, C).
// One wave per chain; lane l owns channels 256q+4l+e (4 coalesced float4s).
// STRIDE/NSTEPS/FWD are compile-time so the per-step store (slice i) and
// prefetch load (slice i+3) addresses differ by a provable nonzero constant
// -> BasicAA proves NoAlias -> no store->load waitcnt serialization.
// All cross-lane traffic is DPP (VALU) instead of ds_bpermute.
template<int NSTEPS, long STRIDE, long COLSTRIDE, bool FWD>
__global__ __launch_bounds__(64) void scan_pass(float* __restrict__ Y,
                                                const float* __restrict__ ktab)
{
    __shared__ float ks_raw[Ww * 5 + 16];
    float* ks = ks_raw + 8;                   // allow kidx = -1 / NSTEPS overread
    const int l = threadIdx.x;

    const float* kt = ktab + (size_t)blockIdx.x * (size_t)(NSTEPS * 5);
    for (int i = l; i < NSTEPS * 5; i += 64) ks[i] = kt[i];
    __syncthreads();

    constexpr long SSTEP = FWD ? STRIDE : -STRIDE;
    constexpr int  KSTEP = FWD ? 1 : -1;
    long cur = (long)blockIdx.x * COLSTRIDE + (FWD ? 0L : (long)(NSTEPS - 1) * STRIDE);
    int kidx = FWD ? 0 : NSTEPS - 1;
    const int loff = 4 * l;

    // step 0: out = x (in-place: nothing to store)
    float4 prev[4];
    #pragma unroll
    for (int q = 0; q < 4; ++q)
        prev[q] = *reinterpret_cast<const float4*>(&Y[cur + q * 256 + loff]);
    float mx = -3.4e38f;
    #pragma unroll
    for (int q = 0; q < 4; ++q)
        mx = fmaxf(mx, fmaxf(fmaxf(prev[q].x, prev[q].y),
                             fmaxf(prev[q].z, prev[q].w)));
    float pmax = waveMaxDpp(mx);

    // prefetch x for steps 1,2,3
    float4 xb0[4], xb1[4], xb2[4];
    #pragma unroll
    for (int q = 0; q < 4; ++q)
        xb0[q] = *reinterpret_cast<const float4*>(&Y[cur + SSTEP + q * 256 + loff]);
    #pragma unroll
    for (int q = 0; q < 4; ++q)
        xb1[q] = *reinterpret_cast<const float4*>(&Y[cur + 2 * SSTEP + q * 256 + loff]);
    #pragma unroll
    for (int q = 0; q < 4; ++q)
        xb2[q] = *reinterpret_cast<const float4*>(&Y[cur + 3 * SSTEP + q * 256 + loff]);

    // prefetch k for step 1
    kidx += KSTEP;
    float pk0 = ks[kidx * 5 + 0], pk1 = ks[kidx * 5 + 1], pk2 = ks[kidx * 5 + 2],
          pk3 = ks[kidx * 5 + 3], pk4 = ks[kidx * 5 + 4];

    cur += SSTEP;   // now at step 1
    int i = 1;

#define STEP(XB)                                                              \
  {                                                                           \
    const float k0 = pk0, k1 = pk1, k2 = pk2, k3 = pk3, k4 = pk4;             \
    kidx += KSTEP;                                                            \
    pk0 = ks[kidx * 5 + 0]; pk1 = ks[kidx * 5 + 1]; pk2 = ks[kidx * 5 + 2];   \
    pk3 = ks[kidx * 5 + 3]; pk4 = ks[kidx * 5 + 4];                           \
    float A[4], B[4];                                                         \
    _Pragma("unroll") for (int q = 0; q < 4; ++q) {                           \
      A[q] = dppRor1(prev[q].w);      /* lane l: prev.w @ (l-1)&63 */         \
      B[q] = dppRol1(prev[q].x);      /* lane l: prev.x @ (l+1)&63 */         \
    }                                                                         \
    float4 pt[4]; float m = -3.4e38f;                                         \
    _Pragma("unroll") for (int q = 0; q < 4; ++q) {                           \
      float pm0 = (l > 0)  ? A[q] : (q > 0 ? A[q - 1] : 0.f);                 \
      float pp3 = (l < 63) ? B[q] : (q < 3 ? B[q + 1] : 0.f);                 \
      float4 p = prev[q], x = XB[q];                                          \
      pt[q].x = k0 * x.x + k1 * p.x + k2 * pm0 + k3 * p.y;                    \
      pt[q].y = k0 * x.y + k1 * p.y + k2 * p.x + k3 * p.z;                    \
      pt[q].z = k0 * x.z + k1 * p.z + k2 * p.y + k3 * p.w;                    \
      pt[q].w = k0 * x.w + k1 * p.w + k2 * p.z + k3 * pp3;                    \
      m = fmaxf(m, fmaxf(fmaxf(pt[q].x, pt[q].y), fmaxf(pt[q].z, pt[q].w)));  \
    }                                                                         \
    if (i + 3 < NSTEPS) {                                                     \
      _Pragma("unroll") for (int q = 0; q < 4; ++q)                           \
        XB[q] = *reinterpret_cast<const float4*>(                             \
            &Y[cur + 3 * SSTEP + q * 256 + loff]);                            \
    }                                                                         \
    float R = waveMaxDpp(m);                                                  \
    _Pragma("unroll") for (int q = 0; q < 4; ++q) {                           \
      prev[q].x = fmaf(k4, pmax, pt[q].x);                                    \
      prev[q].y = fmaf(k4, pmax, pt[q].y);                                    \
      prev[q].z = fmaf(k4, pmax, pt[q].z);                                    \
      prev[q].w = fmaf(k4, pmax, pt[q].w);                                    \
      *reinterpret_cast<float4*>(&Y[cur + q * 256 + loff]) = prev[q];         \
    }                                                                         \
    pmax = fmaf(k4, pmax, R);                                                 \
    cur += SSTEP; ++i;                                                        \
  }

    while (i + 2 < NSTEPS) { STEP(xb0) STEP(xb1) STEP(xb2) }
    if (i < NSTEPS) STEP(xb0)
    if (i < NSTEPS) STEP(xb1)
#undef STEP
}

// ---------------------------------------------------------------------------
extern "C" void kernel_launch(void* const* d_in, const int* in_sizes, int n_in,
                              void* d_out, int out_size, void* d_ws, size_t ws_size,
                              hipStream_t stream)
{
    const float* x = (const float*)d_in[0];   // (1, 32, 32, 128, 160) = (C,H,W)
    const float* g = (const float*)d_in[1];   // (1, 20, 128, 160)
    float* out = (float*)d_out;

    const size_t kn_bytes = (size_t)4 * HWp * 5 * sizeof(float);   // 1.64 MB
    const size_t y_bytes  = (size_t)Cc * HWp * sizeof(float);      // 84 MB
    if (ws_size < kn_bytes + y_bytes) return;

    float* kn = (float*)d_ws;
    float* Y  = (float*)((char*)d_ws + kn_bytes);

    // 1) normalize guidance into per-chain-contiguous tables
    norm_g<<<(HWp + 255) / 256, 256, 0, stream>>>(g, kn);

    // 2) transpose x (C,HW) -> Y (HW,C)
    transpose_in<<<dim3(HWp / 32, Cc / 32), dim3(32, 8), 0, stream>>>(x, Y);

    // 3) four in-place directional scans on Y (strides compile-time)
    scan_pass<Hh, (long)Ww * Cc, (long)Cc, true ><<<Ww, 64, 0, stream>>>(
        Y, kn + (size_t)0 * HWp * 5);
    scan_pass<Hh, (long)Ww * Cc, (long)Cc, false><<<Ww, 64, 0, stream>>>(
        Y, kn + (size_t)1 * HWp * 5);
    scan_pass<Ww, (long)Cc, (long)Ww * Cc, true ><<<Hh, 64, 0, stream>>>(
        Y, kn + (size_t)2 * HWp * 5);
    scan_pass<Ww, (long)Cc, (long)Ww * Cc, false><<<Hh, 64, 0, stream>>>(
        Y, kn + (size_t)3 * HWp * 5);

    // 4) transpose Y (HW,C) -> out (C,HW)
    transpose_out<<<dim3(Cc / 32, HWp / 32), dim3(32, 8), 0, stream>>>(Y, out);
}

// Round 4
// 241.782 us; speedup vs baseline: 1.7018x; 1.1930x over previous
//
#include <hip/hip_runtime.h>

#define Hh 128
#define Ww 160
#define Cc 1024
#define HWp (Hh*Ww)

// ---------------------------------------------------------------------------
// DPP cross-lane helpers (VALU latency, no LDS/ds_bpermute).
template<int CTRL>
__device__ __forceinline__ float dppMaxStage(float v) {
    // invalid lanes receive old = -inf (identity for max)
    int t = __builtin_amdgcn_update_dpp((int)0xFF800000, __float_as_int(v),
                                        CTRL, 0xF, 0xF, false);
    return fmaxf(v, __int_as_float(t));
}
// Wave64 max; result returned as a wave-uniform (SGPR) value.
__device__ __forceinline__ float waveMaxDpp(float v) {
    v = dppMaxStage<0x111>(v);   // row_shr:1
    v = dppMaxStage<0x112>(v);   // row_shr:2
    v = dppMaxStage<0x114>(v);   // row_shr:4
    v = dppMaxStage<0x118>(v);   // row_shr:8
    v = dppMaxStage<0x142>(v);   // row_bcast:15
    v = dppMaxStage<0x143>(v);   // row_bcast:31  -> lane63 = wave max
    return __int_as_float(__builtin_amdgcn_readlane(__float_as_int(v), 63));
}
__device__ __forceinline__ float dppRor1(float v) {  // lane l <- lane (l-1)&63
    return __int_as_float(__builtin_amdgcn_update_dpp(0, __float_as_int(v),
                                                      0x13C, 0xF, 0xF, false));
}
__device__ __forceinline__ float dppRol1(float v) {  // lane l <- lane (l+1)&63
    return __int_as_float(__builtin_amdgcn_update_dpp(0, __float_as_int(v),
                                                      0x134, 0xF, 0xF, false));
}

// ---------------------------------------------------------------------------
// Normalize guidance: g (20, H, W) -> kn tables.
// dir 0,1 (H-scans): kn[d*HW*5 + (t*H + s)*5 + j]   (per-column contiguous)
// dir 2,3 (W-scans): kn[d*HW*5 + (s*W + t)*5 + j]   (per-row contiguous)
__global__ __launch_bounds__(256) void norm_g(const float* __restrict__ g,
                                              float* __restrict__ kn)
{
    int p = blockIdx.x * blockDim.x + threadIdx.x;
    if (p >= HWp) return;
    int s = p / Ww, t = p - s * Ww;
    #pragma unroll
    for (int d = 0; d < 4; ++d) {
        float v[5]; float sum = 0.f;
        #pragma unroll
        for (int j = 0; j < 5; ++j) {
            v[j] = g[(size_t)(5 * d + j) * HWp + p];
            sum += fabsf(v[j]);
        }
        float inv = 1.f / fmaxf(sum, 1e-12f);
        size_t off = (d < 2) ? ((size_t)d * HWp * 5 + ((size_t)t * Hh + s) * 5)
                             : ((size_t)d * HWp * 5 + (size_t)p * 5);
        #pragma unroll
        for (int j = 0; j < 5; ++j) kn[off + j] = v[j] * inv;
    }
}

// ---------------------------------------------------------------------------
// Tiled transposes between (C, HW) and (HW, C).
__global__ __launch_bounds__(256) void transpose_in(const float* __restrict__ in,
                                                    float* __restrict__ out)
{
    __shared__ float tile[32][33];
    int p0 = blockIdx.x * 32, c0 = blockIdx.y * 32;
    int tx = threadIdx.x, ty = threadIdx.y;          // (32, 8)
    #pragma unroll
    for (int i = 0; i < 4; ++i)
        tile[ty + 8 * i][tx] = in[(size_t)(c0 + ty + 8 * i) * HWp + p0 + tx];
    __syncthreads();
    #pragma unroll
    for (int i = 0; i < 4; ++i)
        out[(size_t)(p0 + ty + 8 * i) * Cc + c0 + tx] = tile[tx][ty + 8 * i];
}

__global__ __launch_bounds__(256) void transpose_out(const float* __restrict__ Y,
                                                     float* __restrict__ out)
{
    __shared__ float tile[32][33];
    int c0 = blockIdx.x * 32, p0 = blockIdx.y * 32;
    int tx = threadIdx.x, ty = threadIdx.y;          // (32, 8)
    #pragma unroll
    for (int i = 0; i < 4; ++i)
        tile[ty + 8 * i][tx] = Y[(size_t)(p0 + ty + 8 * i) * Cc + c0 + tx];
    __syncthreads();
    #pragma unroll
    for (int i = 0; i < 4; ++i)
        out[(size_t)(c0 + ty + 8 * i) * HWp + p0 + tx] = tile[tx][ty + 8 * i];
}

// ---------------------------------------------------------------------------
// One directional scan pass, in-place on Y laid out (H, W, C).
// 4 waves per chain (256 threads): thread t owns channels 4t..4t+3 (1 float4),
// wave w owns channels [256w, 256w+256). Depth-4 x-prefetch (4 regs/slice).
// Cross-wave coupling (c+-1 at 256-boundaries, global channel max) goes
// through a tiny ping-pong LDS exchange: per wave {first, last, waveMax(pt)}.
// De-chained max: out_i = pt_i + a_i, a_i = k4_i*M_{i-1},
// M_i = maxAllWaves(pt_i) + a_i (every wave tracks M/a redundantly).
// Barrier: raw s_barrier with lgkmcnt(0) only (NO vmcnt drain -> global
// prefetch loads stay in flight across steps; per-block Y region is private,
// so skipping the vmcnt drain at the barrier is safe).
template<int NSTEPS, long STRIDE, long COLSTRIDE, bool FWD>
__global__ __launch_bounds__(256) void scan_pass(float* __restrict__ Y,
                                                 const float* __restrict__ ktab)
{
    __shared__ float ks_raw[Ww * 5 + 16];
    __shared__ float xch[2][4][4];   // [parity][wave][{first,last,R,pad}]
    float* ks = ks_raw + 8;          // allow kidx = -1 / NSTEPS overread
    const int tid = threadIdx.x;
    const int l = tid & 63;
    const int w = tid >> 6;

    const float* kt = ktab + (size_t)blockIdx.x * (size_t)(NSTEPS * 5);
    for (int i = tid; i < NSTEPS * 5; i += 256) ks[i] = kt[i];

    constexpr long SSTEP = FWD ? STRIDE : -STRIDE;
    constexpr int  KSTEP = FWD ? 1 : -1;
    long cur = (long)blockIdx.x * COLSTRIDE + (FWD ? 0L : (long)(NSTEPS - 1) * STRIDE);
    int kidx = FWD ? 0 : NSTEPS - 1;
    const int off4 = 4 * tid;

    // step 0: out = x (in-place: nothing to store)
    float4 prev = *reinterpret_cast<const float4*>(&Y[cur + off4]);
    // prefetch x slices 1..4
    float4 xb0 = *reinterpret_cast<const float4*>(&Y[cur + 1 * SSTEP + off4]);
    float4 xb1 = *reinterpret_cast<const float4*>(&Y[cur + 2 * SSTEP + off4]);
    float4 xb2 = *reinterpret_cast<const float4*>(&Y[cur + 3 * SSTEP + off4]);
    float4 xb3 = *reinterpret_cast<const float4*>(&Y[cur + 4 * SSTEP + off4]);

    float m0 = fmaxf(fmaxf(prev.x, prev.y), fmaxf(prev.z, prev.w));
    float R0 = waveMaxDpp(m0);
    __syncthreads();                 // ks table ready (full barrier once)
    if (l == 0)  { xch[0][w][0] = prev.x; xch[0][w][2] = R0; }
    if (l == 63) { xch[0][w][1] = prev.w; }
    float a_prev = 0.f;

    // prefetch k for step 1
    kidx += KSTEP;
    float pk0 = ks[kidx * 5 + 0], pk1 = ks[kidx * 5 + 1], pk2 = ks[kidx * 5 + 2],
          pk3 = ks[kidx * 5 + 3], pk4 = ks[kidx * 5 + 4];

    asm volatile("s_waitcnt lgkmcnt(0)\n\ts_barrier" ::: "memory");
    cur += SSTEP;   // now at step 1
    int i = 1;

#define STEP(XB, RP, WP)                                                      \
  {                                                                           \
    const float k0 = pk0, k1 = pk1, k2 = pk2, k3 = pk3, k4 = pk4;             \
    kidx += KSTEP;                                                            \
    pk0 = ks[kidx * 5 + 0]; pk1 = ks[kidx * 5 + 1]; pk2 = ks[kidx * 5 + 2];   \
    pk3 = ks[kidx * 5 + 3]; pk4 = ks[kidx * 5 + 4];                           \
    /* exchange from step i-1 */                                              \
    float nbrLo = (w > 0) ? xch[RP][w - 1][1] : 0.f;                          \
    float nbrHi = (w < 3) ? xch[RP][w + 1][0] : 0.f;                          \
    float Rg = fmaxf(fmaxf(xch[RP][0][2], xch[RP][1][2]),                     \
                     fmaxf(xch[RP][2][2], xch[RP][3][2]));                    \
    float Mp = Rg + a_prev;          /* = max_c(out_{i-1}) */                 \
    float a  = k4 * Mp;                                                       \
    float A = dppRor1(prev.w);       /* lane l: prev.w @ lane l-1 */          \
    float B = dppRol1(prev.x);       /* lane l: prev.x @ lane l+1 */          \
    float pm0 = (l > 0)  ? A : nbrLo;                                         \
    float pp3 = (l < 63) ? B : nbrHi;                                         \
    float4 pt;                                                                \
    pt.x = k0 * XB.x + k1 * prev.x + k2 * pm0    + k3 * prev.y;               \
    pt.y = k0 * XB.y + k1 * prev.y + k2 * prev.x + k3 * prev.z;               \
    pt.z = k0 * XB.z + k1 * prev.z + k2 * prev.y + k3 * prev.w;               \
    pt.w = k0 * XB.w + k1 * prev.w + k2 * prev.z + k3 * pp3;                  \
    float4 o;                                                                 \
    o.x = pt.x + a; o.y = pt.y + a; o.z = pt.z + a; o.w = pt.w + a;           \
    *reinterpret_cast<float4*>(&Y[cur + off4]) = o;                           \
    float m = fmaxf(fmaxf(pt.x, pt.y), fmaxf(pt.z, pt.w));                    \
    float Rw = waveMaxDpp(m);                                                 \
    if (l == 0)  { xch[WP][w][0] = o.x; xch[WP][w][2] = Rw; }                 \
    if (l == 63) { xch[WP][w][1] = o.w; }                                     \
    if (i + 4 < NSTEPS)                                                       \
      XB = *reinterpret_cast<const float4*>(&Y[cur + 4 * SSTEP + off4]);      \
    a_prev = a;                                                               \
    asm volatile("s_waitcnt lgkmcnt(0)\n\ts_barrier" ::: "memory");           \
    prev = o;                                                                 \
    cur += SSTEP; ++i;                                                        \
  }

    // 4x-unrolled: prefetch ring (4) and LDS parity (2) both align.
    while (i + 3 < NSTEPS) {
        STEP(xb0, 0, 1) STEP(xb1, 1, 0) STEP(xb2, 0, 1) STEP(xb3, 1, 0)
    }
    if (i < NSTEPS) STEP(xb0, 0, 1)
    if (i < NSTEPS) STEP(xb1, 1, 0)
    if (i < NSTEPS) STEP(xb2, 0, 1)
#undef STEP
}

// ---------------------------------------------------------------------------
extern "C" void kernel_launch(void* const* d_in, const int* in_sizes, int n_in,
                              void* d_out, int out_size, void* d_ws, size_t ws_size,
                              hipStream_t stream)
{
    const float* x = (const float*)d_in[0];   // (1, 32, 32, 128, 160) = (C,H,W)
    const float* g = (const float*)d_in[1];   // (1, 20, 128, 160)
    float* out = (float*)d_out;

    const size_t kn_bytes = (size_t)4 * HWp * 5 * sizeof(float);   // 1.64 MB
    const size_t y_bytes  = (size_t)Cc * HWp * sizeof(float);      // 84 MB
    if (ws_size < kn_bytes + y_bytes) return;

    float* kn = (float*)d_ws;
    float* Y  = (float*)((char*)d_ws + kn_bytes);

    // 1) normalize guidance into per-chain-contiguous tables
    norm_g<<<(HWp + 255) / 256, 256, 0, stream>>>(g, kn);

    // 2) transpose x (C,HW) -> Y (HW,C)
    transpose_in<<<dim3(HWp / 32, Cc / 32), dim3(32, 8), 0, stream>>>(x, Y);

    // 3) four in-place directional scans on Y (4 waves per chain)
    scan_pass<Hh, (long)Ww * Cc, (long)Cc, true ><<<Ww, 256, 0, stream>>>(
        Y, kn + (size_t)0 * HWp * 5);
    scan_pass<Hh, (long)Ww * Cc, (long)Cc, false><<<Ww, 256, 0, stream>>>(
        Y, kn + (size_t)1 * HWp * 5);
    scan_pass<Ww, (long)Cc, (long)Ww * Cc, true ><<<Hh, 256, 0, stream>>>(
        Y, kn + (size_t)2 * HWp * 5);
    scan_pass<Ww, (long)Cc, (long)Ww * Cc, false><<<Hh, 256, 0, stream>>>(
        Y, kn + (size_t)3 * HWp * 5);

    // 4) transpose Y (HW,C) -> out (C,HW)
    transpose_out<<<dim3(Cc / 32, HWp / 32), dim3(32, 8), 0, stream>>>(Y, out);
}